// Round 12
// baseline (68.477 us; speedup 1.0000x reference)
//
#include <hip/hip_runtime.h>
#include <hip/hip_bf16.h>

#define TT 2048
#define DDIM 1024
#define NHEAD 16
#define HD 64
#define QBLK 64
#define KVBLK 64
#define NQT (TT / QBLK)

typedef float f32x4 __attribute__((ext_vector_type(4)));
typedef short bf16x8 __attribute__((ext_vector_type(8)));

__device__ __forceinline__ ushort f2bf(float f) {
    __hip_bfloat16 h = __float2bfloat16(f);
    return *reinterpret_cast<ushort*>(&h);
}

// barrier WITHOUT the compiler's vmcnt(0) drain (R11-proven: main 84->62us).
__device__ __forceinline__ void barrier_lgkm_only() {
    asm volatile("s_waitcnt lgkmcnt(0)" ::: "memory");
    __builtin_amdgcn_s_barrier();
}

// ============ pre-pass (R8-proven): K -> bf16, V -> bf16 transposed ============
__global__ __launch_bounds__(256)
void prepass_kernel(const float* __restrict__ kg, const float* __restrict__ vg,
                    ushort* __restrict__ kbf, ushort* __restrict__ vt) {
    __shared__ float vtile[64][65];
    const int tid = threadIdx.x;
    const int kv0 = (int)blockIdx.x * 64;
    const int bh  = (int)blockIdx.y;
    const int b = bh >> 4, h = bh & 15;
    const int row = tid >> 2;
    const int c0  = (tid & 3) * 16;
    const size_t gin = ((size_t)(b * TT + kv0 + row)) * DDIM + h * HD + c0;

    {
        ushort o[16];
        #pragma unroll
        for (int i = 0; i < 4; ++i) {
            float4 a = *(const float4*)(kg + gin + i * 4);
            o[i*4+0]=f2bf(a.x); o[i*4+1]=f2bf(a.y); o[i*4+2]=f2bf(a.z); o[i*4+3]=f2bf(a.w);
        }
        ushort* kout = kbf + ((size_t)bh * TT + kv0 + row) * HD + c0;
        *(bf16x8*)kout       = *(bf16x8*)&o[0];
        *(bf16x8*)(kout + 8) = *(bf16x8*)&o[8];
    }
    #pragma unroll
    for (int i = 0; i < 4; ++i) {
        float4 a = *(const float4*)(vg + gin + i * 4);
        vtile[row][c0 + i*4 + 0] = a.x;
        vtile[row][c0 + i*4 + 1] = a.y;
        vtile[row][c0 + i*4 + 2] = a.z;
        vtile[row][c0 + i*4 + 3] = a.w;
    }
    __syncthreads();
    {
        ushort o[16];
        #pragma unroll
        for (int i = 0; i < 16; ++i) o[i] = f2bf(vtile[c0 + i][row]);
        ushort* vout = vt + ((size_t)bh * HD + row) * TT + kv0 + c0;
        *(bf16x8*)vout       = *(bf16x8*)&o[0];
        *(bf16x8*)(vout + 8) = *(bf16x8*)&o[8];
    }
}

// ============ split main: every block <= 16 kv-iters (flash-decoding) ============
// items per bh: id 0..15 upper half of qt=16+id (has diag), 16..31 lower half of
// qt=31-(id-16), 32..47 whole light tile qt=id-32. Heavy items write unnormalized
// partials (po, ml); light items write out directly.
__global__ __launch_bounds__(256, 2)
void attn_split(const float* __restrict__ qg, const ushort* __restrict__ kbf,
                const ushort* __restrict__ vtt, float* __restrict__ po,
                float* __restrict__ ml, float* __restrict__ out) {
    __shared__ __align__(16) ushort lds_k[2][KVBLK * HD];
    __shared__ __align__(16) ushort lds_v[2][HD * KVBLK];
    __shared__ __align__(16) ushort lds_p[4][16 * 64];

    const int tid  = threadIdx.x;
    const int wv   = tid >> 6;
    const int lane = tid & 63;
    const int hi   = lane >> 4;
    const int qr   = lane & 15;

    // decode with XCD locality: 4 bh per XCD (2MB bf16 K+V in one L2)
    const int flat = (int)blockIdx.x;          // 0..1535
    const int xcd  = flat & 7;
    const int i2   = flat >> 3;                // 0..191
    const int bh   = xcd * 4 + (i2 & 3);
    const int id   = i2 >> 2;                  // 0..47
    int qt, lo, thi, part = 0;
    bool hasdiag, heavy;
    if (id < 16)      { qt = 16 + id;        const int n = qt + 1; lo = n >> 1; thi = n;      hasdiag = true;  heavy = true; part = 0; }
    else if (id < 32) { qt = 31 - (id - 16); const int n = qt + 1; lo = 0;      thi = n >> 1; hasdiag = false; heavy = true; part = 1; }
    else              { qt = id - 32;        lo = 0; thi = qt + 1; hasdiag = true; heavy = false; }
    const int nt = thi - lo;
    const int b  = bh >> 4;
    const int h  = bh & 15;
    const int q0 = qt * QBLK;

    const float LOG2E  = 1.4426950408889634f;
    const float slope2 = exp2f(-0.5f * (float)(h + 1)) * LOG2E;
    const float sc2    = 0.125f * LOG2E;
    // hoisted bias constants: c2[i] = i-offset * slope2 (uniform -> SGPR)
    float c2[16];
    #pragma unroll
    for (int st = 0; st < 4; ++st)
        #pragma unroll
        for (int rr = 0; rr < 4; ++rr) c2[st * 4 + rr] = (float)(st * 16 + rr) * slope2;

    // ---- Q fragments ----
    bf16x8 qf[2];
    {
        const float* gq = qg + ((size_t)(b * TT + q0 + wv * 16 + qr)) * DDIM + h * HD + hi * 8;
        #pragma unroll
        for (int ch = 0; ch < 2; ++ch) {
            float4 a0 = *(const float4*)(gq + ch * 32);
            float4 a1 = *(const float4*)(gq + ch * 32 + 4);
            bf16x8 w;
            w[0]=f2bf(a0.x); w[1]=f2bf(a0.y); w[2]=f2bf(a0.z); w[3]=f2bf(a0.w);
            w[4]=f2bf(a1.x); w[5]=f2bf(a1.y); w[6]=f2bf(a1.z); w[7]=f2bf(a1.w);
            qf[ch] = w;
        }
    }

    const ushort* kb = kbf + (size_t)bh * TT * HD;
    const ushort* vb = vtt + (size_t)bh * HD * TT;

    const int srow = tid >> 2;
    const int sci  = tid & 3;

    bf16x8 kr0, kr1, vr0, vr1;
    auto stage_issue = [&](int kv0) {
        const ushort* kp = kb + (size_t)(kv0 + srow) * HD + sci * 8;
        kr0 = *(const bf16x8*)kp;
        kr1 = *(const bf16x8*)(kp + 32);
        const ushort* vp = vb + (size_t)srow * TT + kv0 + sci * 8;
        vr0 = *(const bf16x8*)vp;
        vr1 = *(const bf16x8*)(vp + 32);
    };
    auto stage_write = [&](int nb) {
        const int sw = (srow & 7);
        *(bf16x8*)&lds_k[nb][srow * 64 + ((sci ^ sw) << 3)]       = kr0;
        *(bf16x8*)&lds_k[nb][srow * 64 + (((sci + 4) ^ sw) << 3)] = kr1;
        *(bf16x8*)&lds_v[nb][srow * 64 + ((sci ^ sw) << 3)]       = vr0;
        *(bf16x8*)&lds_v[nb][srow * 64 + (((sci + 4) ^ sw) << 3)] = vr1;
    };

    stage_issue((thi - 1) * KVBLK);
    stage_write(0);

    f32x4 oacc[4] = {};
    float mrun = -INFINITY, lrun = 0.f;
    const int ti = q0 + wv * 16 + qr;

    for (int j = 0; j < nt; ++j) {
        const int buf = j & 1;
        const int t   = thi - 1 - j;                 // descending tile index
        const int kv0 = t * KVBLK;
        if (j + 1 < nt) stage_issue((t - 1) * KVBLK);  // loads in flight ACROSS barrier
        barrier_lgkm_only();

        const bool diag = (j == 0) && hasdiag;

        // ---- S^T = K Q^T ----
        f32x4 sa[4] = {};
        __builtin_amdgcn_s_setprio(1);
        #pragma unroll
        for (int st = 0; st < 4; ++st) {
            if (!diag || st <= wv) {
                const int krow = st * 16 + qr;
                const int sw = (krow & 7);
                bf16x8 k0 = *(const bf16x8*)&lds_k[buf][krow * 64 + ((hi ^ sw) << 3)];
                bf16x8 k1 = *(const bf16x8*)&lds_k[buf][krow * 64 + (((4 + hi) ^ sw) << 3)];
                sa[st] = __builtin_amdgcn_mfma_f32_16x16x32_bf16(k0, qf[0], sa[st], 0, 0, 0);
                sa[st] = __builtin_amdgcn_mfma_f32_16x16x32_bf16(k1, qf[1], sa[st], 0, 0, 0);
            }
        }
        __builtin_amdgcn_s_setprio(0);

        // ---- in-register softmax; exact integer-domain causal mask (R9 lesson) ----
        const float relb  = (float)(kv0 - ti + hi * 4);
        const float relb2 = relb * slope2;
        float xv[16];
        float tm = -INFINITY;
        #pragma unroll
        for (int st = 0; st < 4; ++st)
            #pragma unroll
            for (int rr = 0; rr < 4; ++rr) {
                float v = fmaf(sa[st][rr], sc2, relb2 + c2[st * 4 + rr]);
                if (diag) {
                    const float rel = relb + (float)(st * 16 + rr);   // exact small ints
                    v = (rel <= 0.f) ? v : -INFINITY;
                }
                xv[st * 4 + rr] = v;
                tm = fmaxf(tm, v);
            }
        // NO cross-lane reduce in the common path: __all covers all 64 lanes.
        if (!__all(tm <= mrun + 8.f)) {
            tm = fmaxf(tm, __shfl_xor(tm, 16));
            tm = fmaxf(tm, __shfl_xor(tm, 32));
            const float mnew = fmaxf(mrun, tm);
            const float fsc  = exp2f(mrun - mnew);
            mrun = mnew;
            lrun *= fsc;
            float fo[4];
            #pragma unroll
            for (int rr = 0; rr < 4; ++rr) fo[rr] = __shfl(fsc, hi * 4 + rr);
            #pragma unroll
            for (int dt = 0; dt < 4; ++dt)
                #pragma unroll
                for (int rr = 0; rr < 4; ++rr) oacc[dt][rr] *= fo[rr];
        }
        float psum = 0.f;
        #pragma unroll
        for (int i = 0; i < 16; ++i) { xv[i] = exp2f(xv[i] - mrun); psum += xv[i]; }
        lrun += psum;

        // ---- P -> per-wave LDS ----
        #pragma unroll
        for (int st = 0; st < 4; ++st) {
            ushort4 w;
            w.x = f2bf(xv[st * 4 + 0]); w.y = f2bf(xv[st * 4 + 1]);
            w.z = f2bf(xv[st * 4 + 2]); w.w = f2bf(xv[st * 4 + 3]);
            const int slot8 = (st << 1) | (hi >> 1);
            *(ushort4*)&lds_p[wv][qr * 64 + ((slot8 ^ (qr & 7)) << 3) + ((hi & 1) << 2)] = w;
        }

        // ---- O += P V ----
        __builtin_amdgcn_s_setprio(1);
        #pragma unroll
        for (int ks = 0; ks < 2; ++ks) {
            if (!diag || wv >= 2 || ks == 0) {
                bf16x8 pa = *(const bf16x8*)&lds_p[wv][qr * 64 + ((((ks << 2) | hi) ^ (qr & 7)) << 3)];
                #pragma unroll
                for (int dt = 0; dt < 4; ++dt) {
                    const int dv = dt * 16 + qr;
                    bf16x8 vbf = *(const bf16x8*)&lds_v[buf][dv * 64 + ((((ks << 2) + hi) ^ (dv & 7)) << 3)];
                    oacc[dt] = __builtin_amdgcn_mfma_f32_16x16x32_bf16(pa, vbf, oacc[dt], 0, 0, 0);
                }
            }
        }
        __builtin_amdgcn_s_setprio(0);

        if (j + 1 < nt) stage_write(buf ^ 1);
    }

    // ---- epilogue ----
    float lr = lrun;
    lr += __shfl_xor(lr, 16);
    lr += __shfl_xor(lr, 32);
    if (!heavy) {
        const float linv = 1.0f / lr;
        #pragma unroll
        for (int rr = 0; rr < 4; ++rr) {
            const float inv = __shfl(linv, hi * 4 + rr);
            float* go = out + ((size_t)(b * TT + q0 + wv * 16 + hi * 4 + rr)) * DDIM + h * HD;
            #pragma unroll
            for (int dt = 0; dt < 4; ++dt)
                go[dt * 16 + qr] = oacc[dt][rr] * inv;
        }
    } else {
        float* pbase = po + ((size_t)((part * 32 + bh) * 16 + (qt - 16))) * 4096;
        #pragma unroll
        for (int rr = 0; rr < 4; ++rr) {
            const int row = wv * 16 + hi * 4 + rr;
            #pragma unroll
            for (int dt = 0; dt < 4; ++dt)
                pbase[row * 64 + dt * 16 + qr] = oacc[dt][rr];
        }
        if (hi == 0) {
            float* mlb = ml + ((size_t)((part * 32 + bh) * 16 + (qt - 16))) * 128 + (wv * 16 + qr) * 2;
            mlb[0] = mrun;
            mlb[1] = lr;
        }
    }
}

// ============ combine: merge the two kv-halves of heavy q-tiles ============
__global__ __launch_bounds__(256)
void combine_kernel(const float* __restrict__ po, const float* __restrict__ ml,
                    float* __restrict__ out) {
    const int blk = (int)blockIdx.x;       // 0..511
    const int bh  = blk >> 4;
    const int q16 = blk & 15;
    const int qt  = 16 + q16;
    const int b = bh >> 4, h = bh & 15;
    const int tid = threadIdx.x;
    const int row = tid >> 2;              // 0..63
    const int c0  = (tid & 3) * 16;

    const float* ml0 = ml + ((size_t)((0 * 32 + bh) * 16 + q16)) * 128 + row * 2;
    const float* ml1 = ml + ((size_t)((1 * 32 + bh) * 16 + q16)) * 128 + row * 2;
    const float m0 = ml0[0], l0 = ml0[1];
    const float m1 = ml1[0], l1 = ml1[1];
    const float m  = fmaxf(m0, m1);
    const float a0 = exp2f(m0 - m);
    const float a1 = exp2f(m1 - m);
    const float linv = 1.0f / fmaf(l0, a0, l1 * a1);
    const float s0 = a0 * linv, s1 = a1 * linv;

    const float* p0 = po + ((size_t)((0 * 32 + bh) * 16 + q16) * 64 + row) * 64 + c0;
    const float* p1 = po + ((size_t)((1 * 32 + bh) * 16 + q16) * 64 + row) * 64 + c0;
    float* go = out + ((size_t)(b * TT + qt * 64 + row)) * DDIM + h * HD + c0;
    #pragma unroll
    for (int i = 0; i < 4; ++i) {
        float4 x0 = *(const float4*)(p0 + i * 4);
        float4 x1 = *(const float4*)(p1 + i * 4);
        float4 r;
        r.x = x0.x * s0 + x1.x * s1;
        r.y = x0.y * s0 + x1.y * s1;
        r.z = x0.z * s0 + x1.z * s1;
        r.w = x0.w * s0 + x1.w * s1;
        *(float4*)(go + i * 4) = r;
    }
}

// ============ tier-2 main (R11-proven 62us) if ws < 34MB ============
__global__ __launch_bounds__(256, 2)
void attn_main(const float* __restrict__ qg, const ushort* __restrict__ kbf,
               const ushort* __restrict__ vt, float* __restrict__ out) {
    __shared__ __align__(16) ushort lds_k[2][KVBLK * HD];
    __shared__ __align__(16) ushort lds_v[2][HD * KVBLK];
    __shared__ __align__(16) ushort lds_p[4][16 * 64];

    const int tid  = threadIdx.x;
    const int wv   = tid >> 6;
    const int lane = tid & 63;
    const int hi   = lane >> 4;
    const int qr   = lane & 15;

    const int flat = (int)blockIdx.x;
    const int xcd  = flat & 7;
    const int idx  = flat >> 3;
    const int bs   = idx >> 5;
    const int s    = idx & 31;
    const int bh   = xcd * 4 + bs;
    const int qt   = (bs & 1) ? s : (NQT - 1 - s);
    const int b    = bh >> 4;
    const int h    = bh & 15;
    const int q0   = qt * QBLK;

    const float LOG2E  = 1.4426950408889634f;
    const float slope2 = exp2f(-0.5f * (float)(h + 1)) * LOG2E;
    const float sc2    = 0.125f * LOG2E;

    bf16x8 qf[2];
    {
        const float* gq = qg + ((size_t)(b * TT + q0 + wv * 16 + qr)) * DDIM + h * HD + hi * 8;
        #pragma unroll
        for (int ch = 0; ch < 2; ++ch) {
            float4 a0 = *(const float4*)(gq + ch * 32);
            float4 a1 = *(const float4*)(gq + ch * 32 + 4);
            bf16x8 w;
            w[0]=f2bf(a0.x); w[1]=f2bf(a0.y); w[2]=f2bf(a0.z); w[3]=f2bf(a0.w);
            w[4]=f2bf(a1.x); w[5]=f2bf(a1.y); w[6]=f2bf(a1.z); w[7]=f2bf(a1.w);
            qf[ch] = w;
        }
    }

    const ushort* kb = kbf + (size_t)bh * TT * HD;
    const ushort* vb = vt  + (size_t)bh * HD * TT;

    const int srow = tid >> 2;
    const int sci  = tid & 3;

    bf16x8 kr0, kr1, vr0, vr1;
    auto stage_issue = [&](int kv0) {
        const ushort* kp = kb + (size_t)(kv0 + srow) * HD + sci * 8;
        kr0 = *(const bf16x8*)kp;
        kr1 = *(const bf16x8*)(kp + 32);
        const ushort* vp = vb + (size_t)srow * TT + kv0 + sci * 8;
        vr0 = *(const bf16x8*)vp;
        vr1 = *(const bf16x8*)(vp + 32);
    };
    auto stage_write = [&](int nb) {
        const int sw = (srow & 7);
        *(bf16x8*)&lds_k[nb][srow * 64 + ((sci ^ sw) << 3)]       = kr0;
        *(bf16x8*)&lds_k[nb][srow * 64 + (((sci + 4) ^ sw) << 3)] = kr1;
        *(bf16x8*)&lds_v[nb][srow * 64 + ((sci ^ sw) << 3)]       = vr0;
        *(bf16x8*)&lds_v[nb][srow * 64 + (((sci + 4) ^ sw) << 3)] = vr1;
    };

    const int nit = qt + 1;
    stage_issue(q0);
    stage_write(0);

    f32x4 oacc[4] = {};
    float mrun = -INFINITY, lrun = 0.f;
    const int ti = q0 + wv * 16 + qr;

    for (int j = 0; j < nit; ++j) {
        const int buf = j & 1;
        const int kv0 = q0 - j * KVBLK;
        if (j + 1 < nit) stage_issue(kv0 - KVBLK);
        barrier_lgkm_only();

        const bool diag = (j == 0);

        f32x4 sa[4] = {};
        __builtin_amdgcn_s_setprio(1);
        #pragma unroll
        for (int st = 0; st < 4; ++st) {
            if (!diag || st <= wv) {
                const int krow = st * 16 + qr;
                const int sw = (krow & 7);
                bf16x8 k0 = *(const bf16x8*)&lds_k[buf][krow * 64 + ((hi ^ sw) << 3)];
                bf16x8 k1 = *(const bf16x8*)&lds_k[buf][krow * 64 + (((4 + hi) ^ sw) << 3)];
                sa[st] = __builtin_amdgcn_mfma_f32_16x16x32_bf16(k0, qf[0], sa[st], 0, 0, 0);
                sa[st] = __builtin_amdgcn_mfma_f32_16x16x32_bf16(k1, qf[1], sa[st], 0, 0, 0);
            }
        }
        __builtin_amdgcn_s_setprio(0);

        const float relb = (float)(kv0 - ti + hi * 4);
        float xv[16];
        float tm = -INFINITY;
        #pragma unroll
        for (int st = 0; st < 4; ++st)
            #pragma unroll
            for (int rr = 0; rr < 4; ++rr) {
                const float rel = relb + (float)(st * 16 + rr);
                float v = fmaf(sa[st][rr], sc2, rel * slope2);
                if (diag) v = (rel <= 0.f) ? v : -INFINITY;
                xv[st * 4 + rr] = v;
                tm = fmaxf(tm, v);
            }
        tm = fmaxf(tm, __shfl_xor(tm, 16));
        tm = fmaxf(tm, __shfl_xor(tm, 32));
        if (!__all(tm <= mrun + 8.f)) {
            const float mnew = fmaxf(mrun, tm);
            const float fsc  = exp2f(mrun - mnew);
            mrun = mnew;
            lrun *= fsc;
            float fo[4];
            #pragma unroll
            for (int rr = 0; rr < 4; ++rr) fo[rr] = __shfl(fsc, hi * 4 + rr);
            #pragma unroll
            for (int dt = 0; dt < 4; ++dt)
                #pragma unroll
                for (int rr = 0; rr < 4; ++rr) oacc[dt][rr] *= fo[rr];
        }
        float psum = 0.f;
        #pragma unroll
        for (int i = 0; i < 16; ++i) { xv[i] = exp2f(xv[i] - mrun); psum += xv[i]; }
        lrun += psum;

        #pragma unroll
        for (int st = 0; st < 4; ++st) {
            ushort4 w;
            w.x = f2bf(xv[st * 4 + 0]); w.y = f2bf(xv[st * 4 + 1]);
            w.z = f2bf(xv[st * 4 + 2]); w.w = f2bf(xv[st * 4 + 3]);
            const int slot8 = (st << 1) | (hi >> 1);
            *(ushort4*)&lds_p[wv][qr * 64 + ((slot8 ^ (qr & 7)) << 3) + ((hi & 1) << 2)] = w;
        }

        __builtin_amdgcn_s_setprio(1);
        #pragma unroll
        for (int ks = 0; ks < 2; ++ks) {
            if (!diag || wv >= 2 || ks == 0) {
                bf16x8 pa = *(const bf16x8*)&lds_p[wv][qr * 64 + ((((ks << 2) | hi) ^ (qr & 7)) << 3)];
                #pragma unroll
                for (int dt = 0; dt < 4; ++dt) {
                    const int dv = dt * 16 + qr;
                    bf16x8 vbf = *(const bf16x8*)&lds_v[buf][dv * 64 + ((((ks << 2) + hi) ^ (dv & 7)) << 3)];
                    oacc[dt] = __builtin_amdgcn_mfma_f32_16x16x32_bf16(pa, vbf, oacc[dt], 0, 0, 0);
                }
            }
        }
        __builtin_amdgcn_s_setprio(0);

        if (j + 1 < nit) stage_write(buf ^ 1);
    }

    {
        float lr = lrun;
        lr += __shfl_xor(lr, 16);
        lr += __shfl_xor(lr, 32);
        const float linv = 1.0f / lr;
        #pragma unroll
        for (int rr = 0; rr < 4; ++rr) {
            const float inv = __shfl(linv, hi * 4 + rr);
            float* go = out + ((size_t)(b * TT + q0 + wv * 16 + hi * 4 + rr)) * DDIM + h * HD;
            #pragma unroll
            for (int dt = 0; dt < 4; ++dt)
                go[dt * 16 + qr] = oacc[dt][rr] * inv;
        }
    }
}

extern "C" void kernel_launch(void* const* d_in, const int* in_sizes, int n_in,
                              void* d_out, int out_size, void* d_ws, size_t ws_size,
                              hipStream_t stream) {
    (void)in_sizes; (void)n_in; (void)out_size;
    const float* q = (const float*)d_in[0];
    const float* k = (const float*)d_in[1];
    const float* v = (const float*)d_in[2];
    float* o = (float*)d_out;

    const size_t elems   = (size_t)2 * NHEAD * TT * HD;     // 4.19M per tensor
    const size_t kv_b    = 2 * elems * sizeof(ushort);      // 16.78 MB
    const size_t po_b    = (size_t)2 * 32 * 16 * 64 * 64 * sizeof(float);  // 16.78 MB
    const size_t ml_b    = (size_t)2 * 32 * 16 * 64 * 2 * sizeof(float);   // 0.52 MB
    if (ws_size >= kv_b + po_b + ml_b) {
        ushort* kbf = (ushort*)d_ws;
        ushort* vtt = kbf + elems;
        float*  po  = (float*)((char*)d_ws + kv_b);
        float*  ml  = po + (size_t)2 * 32 * 16 * 64 * 64;
        prepass_kernel<<<dim3(32, 32), 256, 0, stream>>>(k, v, kbf, vtt);
        attn_split<<<dim3(1536), 256, 0, stream>>>(q, kbf, vtt, po, ml, o);
        combine_kernel<<<dim3(512), 256, 0, stream>>>(po, ml, o);
    } else if (ws_size >= kv_b) {
        ushort* kbf = (ushort*)d_ws;
        ushort* vtt = kbf + elems;
        prepass_kernel<<<dim3(32, 32), 256, 0, stream>>>(k, v, kbf, vtt);
        attn_main<<<dim3(1024), 256, 0, stream>>>(q, kbf, vtt, o);
    }
}